// Round 6
// baseline (236.842 us; speedup 1.0000x reference)
//
#include <hip/hip_runtime.h>

// Problem constants: B=1, S=4096, D=1024, H=16, W=512, HD=64, C=8 chunks.
typedef __attribute__((ext_vector_type(8))) short short8;
typedef __attribute__((ext_vector_type(4))) float f32x4;
typedef __attribute__((ext_vector_type(4))) unsigned short us4;
typedef unsigned short u16;

__device__ __forceinline__ u16 f2bf(float f) {
  unsigned int u = __float_as_uint(f);
  u += 0x7fffu + ((u >> 16) & 1u);   // round-to-nearest-even
  return (u16)(u >> 16);
}

// async global->LDS, 16B per lane. LDS dest = wave-uniform base + lane*16.
__device__ __forceinline__ void gld16(const void* g, void* l) {
  __builtin_amdgcn_global_load_lds((const __attribute__((address_space(1))) void*)g,
                                   (__attribute__((address_space(3))) void*)l, 16, 0, 0);
}

// ---------------- cast f32 -> bf16 (8 elems/thread) ----------------
__global__ __launch_bounds__(256) void cast_f32_to_bf16(const float* __restrict__ in,
                                                        u16* __restrict__ out, int n8) {
  int i = blockIdx.x * 256 + threadIdx.x;
  if (i >= n8) return;
  const f32x4* p = (const f32x4*)in;
  f32x4 a = p[i * 2];
  f32x4 b = p[i * 2 + 1];
  short8 o;
#pragma unroll
  for (int j = 0; j < 4; ++j) o[j] = (short)f2bf(a[j]);
#pragma unroll
  for (int j = 0; j < 4; ++j) o[4 + j] = (short)f2bf(b[j]);
  ((short8*)out)[i] = o;
}

// ---------------- transpose [K][N] f32 -> [N][K] bf16 ----------------
__global__ __launch_bounds__(256) void transpose_cast(const float* __restrict__ w,
                                                      u16* __restrict__ wT, int K, int N) {
  __shared__ float tile[32][33];
  int n0 = blockIdx.x * 32, k0 = blockIdx.y * 32;
  int r = threadIdx.x >> 5;   // 0..7
  int c = threadIdx.x & 31;
#pragma unroll
  for (int i = 0; i < 4; ++i)
    tile[r + i * 8][c] = w[(size_t)(k0 + r + i * 8) * N + n0 + c];
  __syncthreads();
#pragma unroll
  for (int i = 0; i < 4; ++i)
    wT[(size_t)(n0 + r + i * 8) * K + k0 + c] = f2bf(tile[c][r + i * 8]);
}

// ---------------- bf16 MFMA GEMM (m97 structure): C = A[M][K] * Bt[N][K]^T ----------------
// BK=64, linear LDS, global_load_lds width-16, 2 barriers per K-step, XCD swizzle.
// MODE 0: f32 C row-major. MODE 1: q (pre-scaled) / k in [16][4096][64]; v as V^T [16][64][4096].
template <int MODE>
__global__ __launch_bounds__(256) void gemm_bf16(
    const u16* __restrict__ A, const u16* __restrict__ Bt, float* __restrict__ C,
    u16* __restrict__ q_out, u16* __restrict__ k_out, u16* __restrict__ v_out,
    int M, int N, int K) {
  __shared__ __align__(16) u16 As[128][64];
  __shared__ __align__(16) u16 Bs[128][64];
  const int t = threadIdx.x;
  const int lane = t & 63;
  const int wid = t >> 6;
  const int wm = wid >> 1, wn = wid & 1;  // 2x2 waves, 64x64 each
  const int l15 = lane & 15, lhi = lane >> 4;

  // XCD-chunked bijective swizzle (grid size % 8 == 0 for both call sites)
  const int nbx = gridDim.x;
  const int bid = blockIdx.y * nbx + blockIdx.x;
  const int cpx = (nbx * gridDim.y) >> 3;
  const int wg = (bid & 7) * cpx + (bid >> 3);
  const int m0 = (wg / nbx) * 128;
  const int n0 = (wg % nbx) * 128;

  const int srow = lane >> 3;           // staging row within 8-row chunk
  const int scol = (lane & 7) * 8;      // staging col (shorts)

  f32x4 acc[4][4];
#pragma unroll
  for (int mi = 0; mi < 4; ++mi)
#pragma unroll
    for (int ni = 0; ni < 4; ++ni) acc[mi][ni] = (f32x4){0.f, 0.f, 0.f, 0.f};

  for (int k0 = 0; k0 < K; k0 += 64) {
    __syncthreads();  // readers done with LDS
#pragma unroll
    for (int i = 0; i < 4; ++i) {
      int cch = wid * 4 + i;            // 16 chunks x 1KB per matrix
      int row = cch * 8 + srow;
      gld16(&A[(size_t)(m0 + row) * K + k0 + scol], &As[cch * 8][0]);
      gld16(&Bt[(size_t)(n0 + row) * K + k0 + scol], &Bs[cch * 8][0]);
    }
    __syncthreads();  // compiler drains vmcnt(0) before barrier
#pragma unroll
    for (int kc = 0; kc < 2; ++kc) {
      short8 af[4], bf[4];
#pragma unroll
      for (int mi = 0; mi < 4; ++mi)
        af[mi] = *(const short8*)&As[wm * 64 + mi * 16 + l15][kc * 32 + lhi * 8];
#pragma unroll
      for (int ni = 0; ni < 4; ++ni)
        bf[ni] = *(const short8*)&Bs[wn * 64 + ni * 16 + l15][kc * 32 + lhi * 8];
#pragma unroll
      for (int mi = 0; mi < 4; ++mi)
#pragma unroll
        for (int ni = 0; ni < 4; ++ni)
          acc[mi][ni] = __builtin_amdgcn_mfma_f32_16x16x32_bf16(af[mi], bf[ni], acc[mi][ni], 0, 0, 0);
    }
  }

  // epilogue; C/D layout: col = lane&15, row = (lane>>4)*4 + reg  [HW-verified]
  const float SCQ = 0.18033688011112042f;  // 0.125 * log2(e), folded into Q
#pragma unroll
  for (int mi = 0; mi < 4; ++mi)
#pragma unroll
    for (int ni = 0; ni < 4; ++ni)
#pragma unroll
      for (int r = 0; r < 4; ++r) {
        int row = m0 + wm * 64 + mi * 16 + lhi * 4 + r;
        int col = n0 + wn * 64 + ni * 16 + l15;
        float val = acc[mi][ni][r];
        if (MODE == 0) {
          C[(size_t)row * N + col] = val;
        } else {
          int which = col >> 10;           // 0:q 1:k 2:v
          int d = col & 1023;
          int hh = d >> 6, hd = d & 63;
          if (which == 0)      q_out[((size_t)hh * 4096 + row) * 64 + hd] = f2bf(val * SCQ);
          else if (which == 1) k_out[((size_t)hh * 4096 + row) * 64 + hd] = f2bf(val);
          else                 v_out[((size_t)hh * 64 + hd) * 4096 + row] = f2bf(val);
        }
      }
}

// ---------------- sliding-window flash attention (LDS-light, barrier-free) ----------------
// Grid: 2048 blocks of 64 threads (1 wave each), XCD-chunked: 2 heads/XCD.
// Wave owns 32 queries (mi=0,1 x 16). Swapped QK^T: sa = mfma(K,Q) -> lane's
// column = ONE query (l15); softmax is lane-local + 2 shfl_xor over the lhi group.
// K and V^T fragments read directly from global (L2-resident); P via per-wave LDS.
__global__ __launch_bounds__(64) void attn_kernel(
    const u16* __restrict__ qh,   // [16][4096][64] bf16, pre-scaled by 0.125*log2e
    const u16* __restrict__ kh,   // [16][4096][64] bf16
    const u16* __restrict__ vt,   // [16][64][4096] bf16 (V^T per head)
    u16* __restrict__ out) {      // [4096][1024] bf16
  __shared__ __align__(16) unsigned int Pl[32][36];  // [q][key-pair] u32 = 2 bf16

  const int lane = threadIdx.x;
  const int l15 = lane & 15, lhi = lane >> 4;

  // XCD-chunked swizzle: XCD x gets wk [x*256,(x+1)*256) = heads {2x, 2x+1}
  const int bid = blockIdx.x;
  const int wk = (bid & 7) * 256 + (bid >> 3);
  const int h = wk >> 7, c = (wk >> 4) & 7, qsub = wk & 15;

  const long head_base = (long)h * 4096 * 64;
  const int qloc0 = qsub * 32;                         // chunk-local query base
  const long q_gbase = head_base + (long)(c * 512 + qloc0) * 64;

  // Q fragments (B-operand: col=l15=query, k=d)
  short8 qf[2][2];
#pragma unroll
  for (int mi = 0; mi < 2; ++mi)
#pragma unroll
    for (int kc = 0; kc < 2; ++kc)
      qf[mi][kc] = *(const short8*)&qh[q_gbase + (long)(16 * mi + l15) * 64 + kc * 32 + lhi * 8];

  float m_run[2] = {-1e30f, -1e30f}, l_run[2] = {0.f, 0.f};
  f32x4 acc[2][4];
#pragma unroll
  for (int mi = 0; mi < 2; ++mi)
#pragma unroll
    for (int nd = 0; nd < 4; ++nd) acc[mi][nd] = (f32x4){0.f, 0.f, 0.f, 0.f};

  const int kt_start = (c == 0) ? 8 : 0;
  const int kt_end = (512 + qloc0 + 31) >> 6;
  const long kv_base = head_base + ((long)c - 1) * 512 * 64;       // K rows (j=0 -> (c-1)*512)
  const long vt_base = (long)h * 64 * 4096 + ((long)c - 1) * 512;  // V^T col offset

  for (int kt = kt_start; kt <= kt_end; ++kt) {
    const int j0 = kt * 64;

    // K fragments (A-operand: row=l15=key, k=d); 8 x 16B direct from global/L2
    short8 kf[4][2];
#pragma unroll
    for (int ni = 0; ni < 4; ++ni)
#pragma unroll
      for (int kc = 0; kc < 2; ++kc)
        kf[ni][kc] = *(const short8*)&kh[kv_base + (long)(j0 + 16 * ni + l15) * 64 + kc * 32 + lhi * 8];
    // V^T fragments (A-operand for PV: row=l15=d, k=key); issued early, used after softmax
    short8 vf[4][2];
#pragma unroll
    for (int nd = 0; nd < 4; ++nd)
#pragma unroll
      for (int kc = 0; kc < 2; ++kc)
        vf[nd][kc] = *(const short8*)&vt[vt_base + (long)(16 * nd + l15) * 4096 + j0 + kc * 32 + lhi * 8];

    // QK^T swapped: sa[mi][ni] = D[row=key(16ni+4lhi+r)][col=query(l15)]
    f32x4 sa[2][4];
#pragma unroll
    for (int mi = 0; mi < 2; ++mi)
#pragma unroll
      for (int ni = 0; ni < 4; ++ni) sa[mi][ni] = (f32x4){0.f, 0.f, 0.f, 0.f};
#pragma unroll
    for (int kc = 0; kc < 2; ++kc)
#pragma unroll
      for (int mi = 0; mi < 2; ++mi)
#pragma unroll
        for (int ni = 0; ni < 4; ++ni)
          sa[mi][ni] = __builtin_amdgcn_mfma_f32_16x16x32_bf16(kf[ni][kc], qf[mi][kc], sa[mi][ni], 0, 0, 0);

    // online softmax, fully lane-local per query (col=l15)
#pragma unroll
    for (int mi = 0; mi < 2; ++mi) {
      const int qloc = qloc0 + 16 * mi + l15;  // chunk-local query pos
      float tm = -1e30f;
      if (j0 + 63 > qloc0 + 16 * mi + 512) {   // boundary tile: apply causal mask
#pragma unroll
        for (int ni = 0; ni < 4; ++ni)
#pragma unroll
          for (int r = 0; r < 4; ++r) {
            int jj = j0 + 16 * ni + 4 * lhi + r;
            float sv = (qloc + 512 >= jj) ? sa[mi][ni][r] : -1e30f;
            sa[mi][ni][r] = sv;
            tm = fmaxf(tm, sv);
          }
      } else {
#pragma unroll
        for (int ni = 0; ni < 4; ++ni)
#pragma unroll
          for (int r = 0; r < 4; ++r) tm = fmaxf(tm, sa[mi][ni][r]);
      }
      tm = fmaxf(tm, __shfl_xor(tm, 16, 64));
      tm = fmaxf(tm, __shfl_xor(tm, 32, 64));
      float mn = fmaxf(m_run[mi], tm);
      float corr = __builtin_amdgcn_exp2f(m_run[mi] - mn);
      m_run[mi] = mn;
      float ls = 0.f;
#pragma unroll
      for (int ni = 0; ni < 4; ++ni)
#pragma unroll
        for (int hh = 0; hh < 2; ++hh) {
          float p0 = __builtin_amdgcn_exp2f(sa[mi][ni][2 * hh] - mn);
          float p1 = __builtin_amdgcn_exp2f(sa[mi][ni][2 * hh + 1] - mn);
          ls += p0 + p1;
          Pl[16 * mi + l15][8 * ni + 2 * lhi + hh] =
              (unsigned int)f2bf(p0) | ((unsigned int)f2bf(p1) << 16);
        }
      ls += __shfl_xor(ls, 16, 64);
      ls += __shfl_xor(ls, 32, 64);
      l_run[mi] = l_run[mi] * corr + ls;
#pragma unroll
      for (int nd = 0; nd < 4; ++nd)
#pragma unroll
        for (int r = 0; r < 4; ++r) acc[mi][nd][r] *= corr;
    }

    // PV: acc[mi][nd] = D[row=d(16nd+4lhi+r)][col=query(l15)] += V^T x P^T
#pragma unroll
    for (int mi = 0; mi < 2; ++mi)
#pragma unroll
      for (int kc = 0; kc < 2; ++kc) {
        short8 pf = *(const short8*)&Pl[16 * mi + l15][kc * 16 + lhi * 4];
#pragma unroll
        for (int nd = 0; nd < 4; ++nd)
          acc[mi][nd] = __builtin_amdgcn_mfma_f32_16x16x32_bf16(vf[nd][kc], pf, acc[mi][nd], 0, 0, 0);
      }
  }

  // epilogue: O^T[d][q] -> out[s][h*64+d], 8B packed stores
#pragma unroll
  for (int mi = 0; mi < 2; ++mi) {
    float inv = 1.f / l_run[mi];
    long s = (long)c * 512 + qloc0 + 16 * mi + l15;
#pragma unroll
    for (int nd = 0; nd < 4; ++nd) {
      us4 o;
#pragma unroll
      for (int r = 0; r < 4; ++r) o[r] = f2bf(acc[mi][nd][r] * inv);
      *(us4*)&out[s * 1024 + h * 64 + 16 * nd + 4 * lhi] = o;
    }
  }
}

extern "C" void kernel_launch(void* const* d_in, const int* in_sizes, int n_in,
                              void* d_out, int out_size, void* d_ws, size_t ws_size,
                              hipStream_t stream) {
  const float* x = (const float*)d_in[0];      // [4096][1024]
  const float* w_qkv = (const float*)d_in[1];  // [1024][3072]
  const float* w_out = (const float*)d_in[2];  // [1024][1024]
  float* out = (float*)d_out;                  // [4096][1024]

  u16* xb = (u16*)d_ws;                        // 4096*1024
  u16* wqkvT = xb + 4096 * 1024;               // [3072][1024]
  u16* woutT = wqkvT + 3072 * 1024;            // [1024][1024]
  u16* qh = woutT + 1024 * 1024;               // [16][4096][64]
  u16* kh = qh + 16 * 4096 * 64;
  u16* vt = kh + 16 * 4096 * 64;               // [16][64][4096] V^T
  u16* attn = xb;  // alias: x_bf16 dead after GEMM1  (total ws = 40 MB)

  cast_f32_to_bf16<<<2048, 256, 0, stream>>>(x, xb, 4096 * 1024 / 8);
  transpose_cast<<<dim3(96, 32), 256, 0, stream>>>(w_qkv, wqkvT, 1024, 3072);
  transpose_cast<<<dim3(32, 32), 256, 0, stream>>>(w_out, woutT, 1024, 1024);

  gemm_bf16<1><<<dim3(24, 32), 256, 0, stream>>>(xb, wqkvT, nullptr, qh, kh, vt,
                                                 4096, 3072, 1024);
  attn_kernel<<<2048, 64, 0, stream>>>(qh, kh, vt, attn);
  gemm_bf16<0><<<dim3(8, 32), 256, 0, stream>>>(attn, woutT, out, nullptr, nullptr, nullptr,
                                                4096, 1024, 1024);
}

// Round 7
// 187.400 us; speedup vs baseline: 1.2638x; 1.2638x over previous
//
#include <hip/hip_runtime.h>

// Problem constants: B=1, S=4096, D=1024, H=16, W=512, HD=64, C=8 chunks.
typedef __attribute__((ext_vector_type(8))) short short8;
typedef __attribute__((ext_vector_type(4))) float f32x4;
typedef unsigned short u16;

__device__ __forceinline__ u16 f2bf(float f) {
  unsigned int u = __float_as_uint(f);
  u += 0x7fffu + ((u >> 16) & 1u);   // round-to-nearest-even
  return (u16)(u >> 16);
}

// async global->LDS, 16B per lane. LDS dest = wave-uniform base + lane*16.
__device__ __forceinline__ void gld16(const void* g, void* l) {
  __builtin_amdgcn_global_load_lds((const __attribute__((address_space(1))) void*)g,
                                   (__attribute__((address_space(3))) void*)l, 16, 0, 0);
}

// ---------------- cast f32 -> bf16 (8 elems/thread) ----------------
__global__ __launch_bounds__(256) void cast_f32_to_bf16(const float* __restrict__ in,
                                                        u16* __restrict__ out, int n8) {
  int i = blockIdx.x * 256 + threadIdx.x;
  if (i >= n8) return;
  const f32x4* p = (const f32x4*)in;
  f32x4 a = p[i * 2];
  f32x4 b = p[i * 2 + 1];
  short8 o;
#pragma unroll
  for (int j = 0; j < 4; ++j) o[j] = (short)f2bf(a[j]);
#pragma unroll
  for (int j = 0; j < 4; ++j) o[4 + j] = (short)f2bf(b[j]);
  ((short8*)out)[i] = o;
}

// ---------------- transpose [K][N] f32 -> [N][K] bf16 ----------------
__global__ __launch_bounds__(256) void transpose_cast(const float* __restrict__ w,
                                                      u16* __restrict__ wT, int K, int N) {
  __shared__ float tile[32][33];
  int n0 = blockIdx.x * 32, k0 = blockIdx.y * 32;
  int r = threadIdx.x >> 5;   // 0..7
  int c = threadIdx.x & 31;
#pragma unroll
  for (int i = 0; i < 4; ++i)
    tile[r + i * 8][c] = w[(size_t)(k0 + r + i * 8) * N + n0 + c];
  __syncthreads();
#pragma unroll
  for (int i = 0; i < 4; ++i)
    wT[(size_t)(n0 + r + i * 8) * K + k0 + c] = f2bf(tile[c][r + i * 8]);
}

// ---------------- per-head V transpose: [16][4096][64] -> [16][64][4096] ----------------
__global__ __launch_bounds__(256) void transpose_v(const u16* __restrict__ vh,
                                                   u16* __restrict__ vt) {
  __shared__ u16 tile[32][33];
  const int s0 = blockIdx.x * 32, d0 = blockIdx.y * 32, h = blockIdx.z;
  const long hb = (long)h * 4096 * 64;
  const long hb2 = (long)h * 64 * 4096;
  const int r = threadIdx.x >> 5, c = threadIdx.x & 31;
#pragma unroll
  for (int i = 0; i < 4; ++i)
    tile[r + i * 8][c] = vh[hb + (long)(s0 + r + i * 8) * 64 + d0 + c];
  __syncthreads();
#pragma unroll
  for (int i = 0; i < 4; ++i)
    vt[hb2 + (long)(d0 + r + i * 8) * 4096 + s0 + c] = tile[c][r + i * 8];
}

// ---------------- bf16 MFMA GEMM: C[M][BNgrid] = A * Bt^T ----------------
// m97 structure + XOR-swizzled LDS (pre-swizzled gld16 source, swizzled frag reads).
// MODE 0: A row-major [M][K], C f32.   MODE 1: A row-major, qkv split epilogue
// (q scaled by 0.125*log2e; q/k/v all [16][4096][64]).  MODE 2: A head-major
// [16][4096][64] (K=1024, BK=64 = one head per k-step), C f32.
template <int MODE, int BN>
__global__ __launch_bounds__(256) void gemm_bf16(
    const u16* __restrict__ A, const u16* __restrict__ Bt, float* __restrict__ C,
    u16* __restrict__ q_out, u16* __restrict__ k_out, u16* __restrict__ v_out,
    int M, int N, int K) {
  __shared__ __align__(16) u16 As[128][64];
  __shared__ __align__(16) u16 Bs[BN][64];
  constexpr int NW = BN / 32;             // N-frags per wave
  const int t = threadIdx.x;
  const int lane = t & 63;
  const int wid = t >> 6;
  const int wm = wid >> 1, wn = wid & 1;  // 2x2 waves
  const int l15 = lane & 15, lhi = lane >> 4;

  // XCD-chunked bijective swizzle (grid sizes are multiples of 8)
  const int nbx = gridDim.x;
  const int bid = blockIdx.y * nbx + blockIdx.x;
  const int cpx = (nbx * gridDim.y) >> 3;
  const int wg = (bid & 7) * cpx + (bid >> 3);
  const int m0 = (wg / nbx) * 128;
  const int n0 = (wg % nbx) * BN;

  const int srow = lane >> 3;                      // staging row within 8-row chunk
  const int scol = ((lane & 7) ^ (lane >> 3)) * 8; // pre-swizzled source unit

  f32x4 acc[4][NW];
#pragma unroll
  for (int mi = 0; mi < 4; ++mi)
#pragma unroll
    for (int ni = 0; ni < NW; ++ni) acc[mi][ni] = (f32x4){0.f, 0.f, 0.f, 0.f};

  for (int k0 = 0; k0 < K; k0 += 64) {
    __syncthreads();  // readers done with LDS
#pragma unroll
    for (int i = 0; i < 4; ++i) {
      int cch = wid * 4 + i;
      int row = cch * 8 + srow;
      const u16* src = (MODE == 2)
          ? &A[((size_t)(k0 >> 6) * 4096 + m0 + row) * 64 + scol]
          : &A[(size_t)(m0 + row) * K + k0 + scol];
      gld16(src, &As[cch * 8][0]);
    }
#pragma unroll
    for (int i = 0; i < NW; ++i) {
      int cch = wid * NW + i;
      int row = cch * 8 + srow;
      gld16(&Bt[(size_t)(n0 + row) * K + k0 + scol], &Bs[cch * 8][0]);
    }
    __syncthreads();
#pragma unroll
    for (int kc = 0; kc < 2; ++kc) {
      short8 af[4], bf[NW];
#pragma unroll
      for (int mi = 0; mi < 4; ++mi) {
        int row = wm * 64 + mi * 16 + l15;
        af[mi] = *(const short8*)&As[row][((kc * 4 + lhi) ^ (l15 & 7)) * 8];
      }
#pragma unroll
      for (int ni = 0; ni < NW; ++ni) {
        int row = wn * (BN / 2) + ni * 16 + l15;
        bf[ni] = *(const short8*)&Bs[row][((kc * 4 + lhi) ^ (l15 & 7)) * 8];
      }
#pragma unroll
      for (int mi = 0; mi < 4; ++mi)
#pragma unroll
        for (int ni = 0; ni < NW; ++ni)
          acc[mi][ni] = __builtin_amdgcn_mfma_f32_16x16x32_bf16(af[mi], bf[ni], acc[mi][ni], 0, 0, 0);
    }
  }

  // epilogue; C/D layout: col = lane&15, row = (lane>>4)*4 + reg  [HW-verified]
  const float SCQ = 0.18033688011112042f;  // 0.125 * log2(e), folded into Q
#pragma unroll
  for (int mi = 0; mi < 4; ++mi)
#pragma unroll
    for (int ni = 0; ni < NW; ++ni)
#pragma unroll
      for (int r = 0; r < 4; ++r) {
        int row = m0 + wm * 64 + mi * 16 + lhi * 4 + r;
        int col = n0 + wn * (BN / 2) + ni * 16 + l15;
        float val = acc[mi][ni][r];
        if constexpr (MODE == 1) {
          int which = col >> 10;           // 0:q 1:k 2:v
          int d = col & 1023;
          int hh = d >> 6, hd = d & 63;
          if (which == 0)      q_out[((size_t)hh * 4096 + row) * 64 + hd] = f2bf(val * SCQ);
          else if (which == 1) k_out[((size_t)hh * 4096 + row) * 64 + hd] = f2bf(val);
          else                 v_out[((size_t)hh * 4096 + row) * 64 + hd] = f2bf(val);
        } else {
          C[(size_t)row * N + col] = val;
        }
      }
}

// ---------------- sliding-window flash attention (round-4 structure) ----------------
// Grid: 512 blocks (XCD-chunked). Block: 4 waves, each owns 32 queries.
// K and V^T both double-buffered in LDS via global_load_lds with pre-swizzled
// source + swizzled frag reads (conflict-free, no scalar transpose work).
// Q pre-scaled by 0.125*log2e. l via all-ones V row MFMA. Output head-major
// over qh (each wave overwrites exactly the q-rows it already read).
__global__ __launch_bounds__(256) void attn_kernel(
    const u16* __restrict__ qh,   // [16][4096][64] bf16 (pre-scaled)
    const u16* __restrict__ kh,   // [16][4096][64] bf16
    const u16* __restrict__ vt,   // [16][64][4096] bf16 (V^T per head)
    u16* __restrict__ outh) {     // [16][4096][64] bf16 (aliases qh)
  __shared__ __align__(16) u16 Ks[2][64][64];     // 16KB
  __shared__ __align__(16) u16 Vt[2][65][64];     // 16.6KB; row 64 = ones
  __shared__ __align__(16) u16 Pl[4][32][72];     // 18KB per-wave P tiles

  const int t = threadIdx.x;
  const int lane = t & 63;
  const int w = t >> 6;
  const int l15 = lane & 15;
  const int lhi = lane >> 4;

  // XCD-chunked swizzle: 2 heads per XCD -> K/V working set ~2MB < 4MB L2
  const int bid = blockIdx.x;
  const int wk = (bid & 7) * 64 + (bid >> 3);
  const int qt = wk & 3, c = (wk >> 2) & 7, h = wk >> 5;

  const long head_base = (long)h * 4096 * 64;
  const int q0 = qt * 128;  // query offset within chunk
  const long q_gbase = head_base + (long)(c * 512 + q0) * 64;

  // Q fragments straight to registers
  short8 qf[2][2];
#pragma unroll
  for (int mi = 0; mi < 2; ++mi)
#pragma unroll
    for (int kc = 0; kc < 2; ++kc)
      qf[mi][kc] = *(const short8*)&qh[q_gbase + (long)(w * 32 + mi * 16 + l15) * 64 + kc * 32 + lhi * 8];

  // ones rows (both buffers): bf16(1.0) = 0x3F80
  if (t < 128) Vt[t >> 6][64][t & 63] = 0x3F80;

  float m_run[8];
  f32x4 acc_o[2][4], acc_l[2];
#pragma unroll
  for (int i = 0; i < 8; ++i) m_run[i] = -1e30f;
#pragma unroll
  for (int mi = 0; mi < 2; ++mi) {
    acc_l[mi] = (f32x4){0.f, 0.f, 0.f, 0.f};
#pragma unroll
    for (int ni = 0; ni < 4; ++ni) acc_o[mi][ni] = (f32x4){0.f, 0.f, 0.f, 0.f};
  }

  const int kt_start = (c == 0) ? 8 : 0;     // chunk 0: no prev chunk
  const int kt_end = 2 * qt + 9;             // causal trim
  const long kv_base = head_base + ((long)c - 1) * 512 * 64;       // K rows
  const long vt_hb = (long)h * 64 * 4096 + ((long)c - 1) * 512;    // V^T cols

  const int srow = lane >> 3;                           // 0..7 within chunk
  const int sunit8 = ((lane & 7) ^ (lane >> 3)) * 8;    // pre-swizzled source unit

  // prologue: stage tile kt_start into buffer 0 (K rows + V^T d-rows)
  {
    const int j0 = kt_start * 64;
#pragma unroll
    for (int i = 0; i < 2; ++i) {
      int cch = w * 2 + i;
      gld16(&kh[kv_base + (long)(j0 + cch * 8 + srow) * 64 + sunit8], &Ks[0][cch * 8][0]);
      gld16(&vt[vt_hb + (long)(cch * 8 + srow) * 4096 + j0 + sunit8], &Vt[0][cch * 8][0]);
    }
  }
  __syncthreads();

  int cur = 0;
  for (int kt = kt_start; kt <= kt_end; ++kt) {
    const int j0 = kt * 64;
    const int nxt = cur ^ 1;

    // issue next tile's async loads early; latency hides under this tile's compute
    if (kt < kt_end) {
      const int j0n = j0 + 64;
#pragma unroll
      for (int i = 0; i < 2; ++i) {
        int cch = w * 2 + i;
        gld16(&kh[kv_base + (long)(j0n + cch * 8 + srow) * 64 + sunit8], &Ks[nxt][cch * 8][0]);
        gld16(&vt[vt_hb + (long)(cch * 8 + srow) * 4096 + j0n + sunit8], &Vt[nxt][cch * 8][0]);
      }
    }

    const bool active = (j0 <= q0 + w * 32 + 31 + 512);  // wave-level causal skip
    if (active) {
      // QK^T: 32 queries x 64 keys per wave (swizzled K reads)
      f32x4 sa[2][4];
#pragma unroll
      for (int mi = 0; mi < 2; ++mi)
#pragma unroll
        for (int ni = 0; ni < 4; ++ni) sa[mi][ni] = (f32x4){0.f, 0.f, 0.f, 0.f};
#pragma unroll
      for (int kc = 0; kc < 2; ++kc) {
        short8 kf[4];
#pragma unroll
        for (int ni = 0; ni < 4; ++ni) {
          int row = ni * 16 + l15;
          kf[ni] = *(const short8*)&Ks[cur][row][((kc * 4 + lhi) ^ (l15 & 7)) * 8];
        }
#pragma unroll
        for (int mi = 0; mi < 2; ++mi)
#pragma unroll
          for (int ni = 0; ni < 4; ++ni)
            sa[mi][ni] = __builtin_amdgcn_mfma_f32_16x16x32_bf16(qf[mi][kc], kf[ni], sa[mi][ni], 0, 0, 0);
      }

      // mask (boundary tiles only; Q pre-scaled so S already in log2 domain)
      const int qrow0 = q0 + w * 32 + lhi * 4;
      const bool need_mask = (j0 + 63 > q0 + w * 32 + 512);
      float tmax[8];
#pragma unroll
      for (int i = 0; i < 8; ++i) tmax[i] = -1e30f;
      if (need_mask) {
#pragma unroll
        for (int mi = 0; mi < 2; ++mi)
#pragma unroll
          for (int ni = 0; ni < 4; ++ni) {
            int jj = j0 + ni * 16 + l15;
#pragma unroll
            for (int r = 0; r < 4; ++r) {
              float sv = sa[mi][ni][r];
              sv = (qrow0 + mi * 16 + r + 512 >= jj) ? sv : -1e30f;
              sa[mi][ni][r] = sv;
              tmax[mi * 4 + r] = fmaxf(tmax[mi * 4 + r], sv);
            }
          }
      } else {
#pragma unroll
        for (int mi = 0; mi < 2; ++mi)
#pragma unroll
          for (int ni = 0; ni < 4; ++ni)
#pragma unroll
            for (int r = 0; r < 4; ++r)
              tmax[mi * 4 + r] = fmaxf(tmax[mi * 4 + r], sa[mi][ni][r]);
      }
#pragma unroll
      for (int i = 0; i < 8; ++i)
#pragma unroll
        for (int d = 1; d < 16; d <<= 1)
          tmax[i] = fmaxf(tmax[i], __shfl_xor(tmax[i], d, 64));

      float corr[8];
#pragma unroll
      for (int i = 0; i < 8; ++i) {
        float mn = fmaxf(m_run[i], tmax[i]);
        corr[i] = __builtin_amdgcn_exp2f(m_run[i] - mn);
        m_run[i] = mn;
      }
#pragma unroll
      for (int mi = 0; mi < 2; ++mi)
#pragma unroll
        for (int ni = 0; ni < 4; ++ni)
#pragma unroll
          for (int r = 0; r < 4; ++r) {
            float p = __builtin_amdgcn_exp2f(sa[mi][ni][r] - m_run[mi * 4 + r]);
            Pl[w][mi * 16 + lhi * 4 + r][ni * 16 + l15] = f2bf(p);
          }
#pragma unroll
      for (int mi = 0; mi < 2; ++mi) {
#pragma unroll
        for (int r = 0; r < 4; ++r) acc_l[mi][r] *= corr[mi * 4 + r];
#pragma unroll
        for (int ni = 0; ni < 4; ++ni)
#pragma unroll
          for (int r = 0; r < 4; ++r) acc_o[mi][ni][r] *= corr[mi * 4 + r];
      }

      // PV: O[32][64] += P[32][64] * V[64][64]; l via all-ones row 64
#pragma unroll
      for (int k2 = 0; k2 < 2; ++k2) {
        short8 pf[2];
#pragma unroll
        for (int mi = 0; mi < 2; ++mi)
          pf[mi] = *(const short8*)&Pl[w][mi * 16 + l15][k2 * 32 + lhi * 8];
        short8 vones = *(const short8*)&Vt[cur][64][k2 * 32 + lhi * 8];
#pragma unroll
        for (int mi = 0; mi < 2; ++mi)
          acc_l[mi] = __builtin_amdgcn_mfma_f32_16x16x32_bf16(pf[mi], vones, acc_l[mi], 0, 0, 0);
#pragma unroll
        for (int ni = 0; ni < 4; ++ni) {
          int row = ni * 16 + l15;
          short8 vf = *(const short8*)&Vt[cur][row][((k2 * 4 + lhi) ^ (l15 & 7)) * 8];
#pragma unroll
          for (int mi = 0; mi < 2; ++mi)
            acc_o[mi][ni] = __builtin_amdgcn_mfma_f32_16x16x32_bf16(pf[mi], vf, acc_o[mi][ni], 0, 0, 0);
        }
      }
    }
    __syncthreads();  // cur reads done everywhere; nxt async writes landed
    cur = nxt;
  }

  // normalize + write head-major [16][4096][64] (same rows this wave read as Q)
#pragma unroll
  for (int mi = 0; mi < 2; ++mi)
#pragma unroll
    for (int ni = 0; ni < 4; ++ni)
#pragma unroll
      for (int r = 0; r < 4; ++r) {
        int qq = q0 + w * 32 + mi * 16 + lhi * 4 + r;
        long s = (long)c * 512 + qq;
        float o = acc_o[mi][ni][r] / acc_l[mi][r];
        outh[(head_base + s * 64) + ni * 16 + l15] = f2bf(o);
      }
}

extern "C" void kernel_launch(void* const* d_in, const int* in_sizes, int n_in,
                              void* d_out, int out_size, void* d_ws, size_t ws_size,
                              hipStream_t stream) {
  const float* x = (const float*)d_in[0];      // [4096][1024]
  const float* w_qkv = (const float*)d_in[1];  // [1024][3072]
  const float* w_out = (const float*)d_in[2];  // [1024][1024]
  float* out = (float*)d_out;                  // [4096][1024]

  u16* xb = (u16*)d_ws;                        // 4M elems
  u16* wqkvT = xb + 4096 * 1024;               // 3M
  u16* woutT = wqkvT + 3072 * 1024;            // 1M
  u16* qh = woutT + 1024 * 1024;               // 4M  (later: attn out, head-major)
  u16* kh = qh + 16 * 4096 * 64;               // 4M
  u16* vh = kh + 16 * 4096 * 64;               // 4M
  u16* vt = xb;  // alias: x_bf16 dead after GEMM1   (total ws = 40 MB)

  cast_f32_to_bf16<<<2048, 256, 0, stream>>>(x, xb, 4096 * 1024 / 8);
  transpose_cast<<<dim3(96, 32), 256, 0, stream>>>(w_qkv, wqkvT, 1024, 3072);
  transpose_cast<<<dim3(32, 32), 256, 0, stream>>>(w_out, woutT, 1024, 1024);

  gemm_bf16<1, 128><<<dim3(24, 32), 256, 0, stream>>>(xb, wqkvT, nullptr, qh, kh, vh,
                                                      4096, 3072, 1024);
  transpose_v<<<dim3(128, 2, 16), 256, 0, stream>>>(vh, vt);
  attn_kernel<<<512, 256, 0, stream>>>(qh, kh, vt, qh);
  gemm_bf16<2, 64><<<dim3(16, 32), 256, 0, stream>>>(qh, woutT, out, nullptr, nullptr, nullptr,
                                                     4096, 1024, 1024);
}

// Round 8
// 182.498 us; speedup vs baseline: 1.2978x; 1.0269x over previous
//
#include <hip/hip_runtime.h>

// Problem constants: B=1, S=4096, D=1024, H=16, W=512, HD=64, C=8 chunks.
typedef __attribute__((ext_vector_type(8))) short short8;
typedef __attribute__((ext_vector_type(4))) float f32x4;
typedef __attribute__((ext_vector_type(4))) unsigned short us4;
typedef unsigned short u16;

__device__ __forceinline__ u16 f2bf(float f) {
  unsigned int u = __float_as_uint(f);
  u += 0x7fffu + ((u >> 16) & 1u);   // round-to-nearest-even
  return (u16)(u >> 16);
}

// async global->LDS, 16B per lane. LDS dest = wave-uniform base + lane*16.
__device__ __forceinline__ void gld16(const void* g, void* l) {
  __builtin_amdgcn_global_load_lds((const __attribute__((address_space(1))) void*)g,
                                   (__attribute__((address_space(3))) void*)l, 16, 0, 0);
}

// ---------------- cast f32 -> bf16 (8 elems/thread) ----------------
__global__ __launch_bounds__(256) void cast_f32_to_bf16(const float* __restrict__ in,
                                                        u16* __restrict__ out, int n8) {
  int i = blockIdx.x * 256 + threadIdx.x;
  if (i >= n8) return;
  const f32x4* p = (const f32x4*)in;
  f32x4 a = p[i * 2];
  f32x4 b = p[i * 2 + 1];
  short8 o;
#pragma unroll
  for (int j = 0; j < 4; ++j) o[j] = (short)f2bf(a[j]);
#pragma unroll
  for (int j = 0; j < 4; ++j) o[4 + j] = (short)f2bf(b[j]);
  ((short8*)out)[i] = o;
}

// ---------------- transpose [K][N] f32 -> [N][K] bf16 ----------------
__global__ __launch_bounds__(256) void transpose_cast(const float* __restrict__ w,
                                                      u16* __restrict__ wT, int K, int N) {
  __shared__ float tile[32][33];
  int n0 = blockIdx.x * 32, k0 = blockIdx.y * 32;
  int r = threadIdx.x >> 5;   // 0..7
  int c = threadIdx.x & 31;
#pragma unroll
  for (int i = 0; i < 4; ++i)
    tile[r + i * 8][c] = w[(size_t)(k0 + r + i * 8) * N + n0 + c];
  __syncthreads();
#pragma unroll
  for (int i = 0; i < 4; ++i)
    wT[(size_t)(n0 + r + i * 8) * K + k0 + c] = f2bf(tile[c][r + i * 8]);
}

// ---------------- per-head V transpose: [16][4096][64] -> [16][64][4096] ----------------
__global__ __launch_bounds__(256) void transpose_v(const u16* __restrict__ vh,
                                                   u16* __restrict__ vt) {
  __shared__ u16 tile[32][33];
  const int s0 = blockIdx.x * 32, d0 = blockIdx.y * 32, h = blockIdx.z;
  const long hb = (long)h * 4096 * 64;
  const long hb2 = (long)h * 64 * 4096;
  const int r = threadIdx.x >> 5, c = threadIdx.x & 31;
#pragma unroll
  for (int i = 0; i < 4; ++i)
    tile[r + i * 8][c] = vh[hb + (long)(s0 + r + i * 8) * 64 + d0 + c];
  __syncthreads();
#pragma unroll
  for (int i = 0; i < 4; ++i)
    vt[hb2 + (long)(d0 + r + i * 8) * 4096 + s0 + c] = tile[c][r + i * 8];
}

// ---------------- bf16 MFMA GEMM: C[M][BNgrid] = A * Bt^T ----------------
// m97 structure + XOR-swizzled LDS (pre-swizzled gld16 source, swizzled frag reads).
// MODE 0: A row-major [M][K], C f32.   MODE 1: A row-major, qkv split epilogue
// (q scaled by 0.125*log2e; q/k/v all [16][4096][64]).  MODE 2: A head-major
// [16][4096][64] (K=1024, BK=64 = one head per k-step), C f32.
template <int MODE, int BN>
__global__ __launch_bounds__(256) void gemm_bf16(
    const u16* __restrict__ A, const u16* __restrict__ Bt, float* __restrict__ C,
    u16* __restrict__ q_out, u16* __restrict__ k_out, u16* __restrict__ v_out,
    int M, int N, int K) {
  __shared__ __align__(16) u16 As[128][64];
  __shared__ __align__(16) u16 Bs[BN][64];
  constexpr int NW = BN / 32;             // N-frags per wave
  const int t = threadIdx.x;
  const int lane = t & 63;
  const int wid = t >> 6;
  const int wm = wid >> 1, wn = wid & 1;  // 2x2 waves
  const int l15 = lane & 15, lhi = lane >> 4;

  // XCD-chunked bijective swizzle (grid sizes are multiples of 8)
  const int nbx = gridDim.x;
  const int bid = blockIdx.y * nbx + blockIdx.x;
  const int cpx = (nbx * gridDim.y) >> 3;
  const int wg = (bid & 7) * cpx + (bid >> 3);
  const int m0 = (wg / nbx) * 128;
  const int n0 = (wg % nbx) * BN;

  const int srow = lane >> 3;                      // staging row within 8-row chunk
  const int scol = ((lane & 7) ^ (lane >> 3)) * 8; // pre-swizzled source unit

  f32x4 acc[4][NW];
#pragma unroll
  for (int mi = 0; mi < 4; ++mi)
#pragma unroll
    for (int ni = 0; ni < NW; ++ni) acc[mi][ni] = (f32x4){0.f, 0.f, 0.f, 0.f};

  for (int k0 = 0; k0 < K; k0 += 64) {
    __syncthreads();  // readers done with LDS
#pragma unroll
    for (int i = 0; i < 4; ++i) {
      int cch = wid * 4 + i;
      int row = cch * 8 + srow;
      const u16* src = (MODE == 2)
          ? &A[((size_t)(k0 >> 6) * 4096 + m0 + row) * 64 + scol]
          : &A[(size_t)(m0 + row) * K + k0 + scol];
      gld16(src, &As[cch * 8][0]);
    }
#pragma unroll
    for (int i = 0; i < NW; ++i) {
      int cch = wid * NW + i;
      int row = cch * 8 + srow;
      gld16(&Bt[(size_t)(n0 + row) * K + k0 + scol], &Bs[cch * 8][0]);
    }
    __syncthreads();
#pragma unroll
    for (int kc = 0; kc < 2; ++kc) {
      short8 af[4], bf[NW];
#pragma unroll
      for (int mi = 0; mi < 4; ++mi) {
        int row = wm * 64 + mi * 16 + l15;
        af[mi] = *(const short8*)&As[row][((kc * 4 + lhi) ^ (l15 & 7)) * 8];
      }
#pragma unroll
      for (int ni = 0; ni < NW; ++ni) {
        int row = wn * (BN / 2) + ni * 16 + l15;
        bf[ni] = *(const short8*)&Bs[row][((kc * 4 + lhi) ^ (l15 & 7)) * 8];
      }
#pragma unroll
      for (int mi = 0; mi < 4; ++mi)
#pragma unroll
        for (int ni = 0; ni < NW; ++ni)
          acc[mi][ni] = __builtin_amdgcn_mfma_f32_16x16x32_bf16(af[mi], bf[ni], acc[mi][ni], 0, 0, 0);
    }
  }

  // epilogue; C/D layout: col = lane&15, row = (lane>>4)*4 + reg  [HW-verified]
  const float SCQ = 0.18033688011112042f;  // 0.125 * log2(e), folded into Q
#pragma unroll
  for (int mi = 0; mi < 4; ++mi)
#pragma unroll
    for (int ni = 0; ni < NW; ++ni)
#pragma unroll
      for (int r = 0; r < 4; ++r) {
        int row = m0 + wm * 64 + mi * 16 + lhi * 4 + r;
        int col = n0 + wn * (BN / 2) + ni * 16 + l15;
        float val = acc[mi][ni][r];
        if constexpr (MODE == 1) {
          int which = col >> 10;           // 0:q 1:k 2:v
          int d = col & 1023;
          int hh = d >> 6, hd = d & 63;
          if (which == 0)      q_out[((size_t)hh * 4096 + row) * 64 + hd] = f2bf(val * SCQ);
          else if (which == 1) k_out[((size_t)hh * 4096 + row) * 64 + hd] = f2bf(val);
          else                 v_out[((size_t)hh * 4096 + row) * 64 + hd] = f2bf(val);
        } else {
          C[(size_t)row * N + col] = val;
        }
      }
}

// ---------------- sliding-window flash attention (swapped-QK^T softmax) ----------------
// Grid: 512 blocks (XCD-chunked). Block: 4 waves, each owns 32 queries.
// K and V^T double-buffered via global_load_lds (pre-swizzled source + swizzled
// reads). QK^T computed SWAPPED: mfma(K,Q) -> lane's column = ONE query, so
// row max/sum are lane-local trees + 2 shfl_xor. P packed to u32 pairs in LDS
// (B-operand layout for PV). PV swapped too: D[d][q]; head-major output.
__global__ __launch_bounds__(256) void attn_kernel(
    const u16* __restrict__ qh,   // [16][4096][64] bf16 (pre-scaled)
    const u16* __restrict__ kh,   // [16][4096][64] bf16
    const u16* __restrict__ vt,   // [16][64][4096] bf16 (V^T per head)
    u16* __restrict__ outh) {     // [16][4096][64] bf16 (aliases qh)
  __shared__ __align__(16) u16 Ks[2][64][64];        // 16KB
  __shared__ __align__(16) u16 Vt[2][64][64];        // 16KB
  __shared__ __align__(16) unsigned int Pl[4][32][37];  // 18.5KB; [wave][q][key-pair]

  const int t = threadIdx.x;
  const int lane = t & 63;
  const int w = t >> 6;
  const int l15 = lane & 15;
  const int lhi = lane >> 4;

  // XCD-chunked swizzle: 2 heads per XCD -> K/V working set ~2MB < 4MB L2
  const int bid = blockIdx.x;
  const int wk = (bid & 7) * 64 + (bid >> 3);
  const int qt = wk & 3, c = (wk >> 2) & 7, h = wk >> 5;

  const long head_base = (long)h * 4096 * 64;
  const int q0 = qt * 128;  // query offset within chunk
  const long q_gbase = head_base + (long)(c * 512 + q0) * 64;

  // Q fragments (used as B-operand: row=l15=query, k=d)
  short8 qf[2][2];
#pragma unroll
  for (int mi = 0; mi < 2; ++mi)
#pragma unroll
    for (int kc = 0; kc < 2; ++kc)
      qf[mi][kc] = *(const short8*)&qh[q_gbase + (long)(w * 32 + mi * 16 + l15) * 64 + kc * 32 + lhi * 8];

  float m_run[2] = {-1e30f, -1e30f}, l_run[2] = {0.f, 0.f};
  f32x4 acc_o[2][4];  // [mi][nd]: D[d=nd*16+lhi*4+r][q=mi*16+l15]
#pragma unroll
  for (int mi = 0; mi < 2; ++mi)
#pragma unroll
    for (int nd = 0; nd < 4; ++nd) acc_o[mi][nd] = (f32x4){0.f, 0.f, 0.f, 0.f};

  const int kt_start = (c == 0) ? 8 : 0;     // chunk 0: no prev chunk
  const int kt_end = 2 * qt + 9;             // causal trim
  const long kv_base = head_base + ((long)c - 1) * 512 * 64;       // K rows
  const long vt_hb = (long)h * 64 * 4096 + ((long)c - 1) * 512;    // V^T cols

  const int srow = lane >> 3;                           // 0..7 within chunk
  const int sunit8 = ((lane & 7) ^ (lane >> 3)) * 8;    // pre-swizzled source unit

  // prologue: stage tile kt_start into buffer 0 (K rows + V^T d-rows)
  {
    const int j0 = kt_start * 64;
#pragma unroll
    for (int i = 0; i < 2; ++i) {
      int cch = w * 2 + i;
      gld16(&kh[kv_base + (long)(j0 + cch * 8 + srow) * 64 + sunit8], &Ks[0][cch * 8][0]);
      gld16(&vt[vt_hb + (long)(cch * 8 + srow) * 4096 + j0 + sunit8], &Vt[0][cch * 8][0]);
    }
  }
  __syncthreads();

  int cur = 0;
  for (int kt = kt_start; kt <= kt_end; ++kt) {
    const int j0 = kt * 64;
    const int nxt = cur ^ 1;

    // issue next tile's async loads early; latency hides under this tile's compute
    if (kt < kt_end) {
      const int j0n = j0 + 64;
#pragma unroll
      for (int i = 0; i < 2; ++i) {
        int cch = w * 2 + i;
        gld16(&kh[kv_base + (long)(j0n + cch * 8 + srow) * 64 + sunit8], &Ks[nxt][cch * 8][0]);
        gld16(&vt[vt_hb + (long)(cch * 8 + srow) * 4096 + j0n + sunit8], &Vt[nxt][cch * 8][0]);
      }
    }

    const bool active = (j0 <= q0 + w * 32 + 31 + 512);  // wave-level causal skip
    if (active) {
      // QK^T swapped: sa[mi][ni] = D[key=j0+16ni+4lhi+r][query=w*32+mi*16+l15]
      f32x4 sa[2][4];
#pragma unroll
      for (int mi = 0; mi < 2; ++mi)
#pragma unroll
        for (int ni = 0; ni < 4; ++ni) sa[mi][ni] = (f32x4){0.f, 0.f, 0.f, 0.f};
#pragma unroll
      for (int kc = 0; kc < 2; ++kc) {
        short8 kf[4];
#pragma unroll
        for (int ni = 0; ni < 4; ++ni) {
          int row = ni * 16 + l15;
          kf[ni] = *(const short8*)&Ks[cur][row][((kc * 4 + lhi) ^ (l15 & 7)) * 8];
        }
#pragma unroll
        for (int mi = 0; mi < 2; ++mi)
#pragma unroll
          for (int ni = 0; ni < 4; ++ni)
            sa[mi][ni] = __builtin_amdgcn_mfma_f32_16x16x32_bf16(kf[ni], qf[mi][kc], sa[mi][ni], 0, 0, 0);
      }

      const bool need_mask = (j0 + 63 > q0 + w * 32 + 512);
#pragma unroll
      for (int mi = 0; mi < 2; ++mi) {
        const int qloc = q0 + w * 32 + mi * 16 + l15;  // this lane's query
        if (need_mask) {
          const int lim = qloc + 512 - j0 - 4 * lhi;   // key-off (16ni+r) <= lim
#pragma unroll
          for (int ni = 0; ni < 4; ++ni)
#pragma unroll
            for (int r = 0; r < 4; ++r)
              if (16 * ni + r > lim) sa[mi][ni][r] = -1e30f;
        }
        // lane-local max tree over 16 values, then 2-round shfl across lhi group
        float v[16];
#pragma unroll
        for (int ni = 0; ni < 4; ++ni)
#pragma unroll
          for (int r = 0; r < 4; ++r) v[ni * 4 + r] = sa[mi][ni][r];
#pragma unroll
        for (int s = 8; s >= 1; s >>= 1)
#pragma unroll
          for (int k = 0; k < s; ++k) v[k] = fmaxf(v[k], v[k + s]);
        float tm = v[0];
        tm = fmaxf(tm, __shfl_xor(tm, 16, 64));
        tm = fmaxf(tm, __shfl_xor(tm, 32, 64));

        float mn = fmaxf(m_run[mi], tm);
        float corr = __builtin_amdgcn_exp2f(m_run[mi] - mn);
        m_run[mi] = mn;

        // P = exp2(S - m), pack pairs (r0,r1),(r2,r3) -> u32, lane-local sum tree
        float ps[16];
#pragma unroll
        for (int ni = 0; ni < 4; ++ni) {
#pragma unroll
          for (int r = 0; r < 4; ++r) ps[ni * 4 + r] = __builtin_amdgcn_exp2f(sa[mi][ni][r] - mn);
          unsigned int p01 = (unsigned int)f2bf(ps[ni * 4 + 0]) | ((unsigned int)f2bf(ps[ni * 4 + 1]) << 16);
          unsigned int p23 = (unsigned int)f2bf(ps[ni * 4 + 2]) | ((unsigned int)f2bf(ps[ni * 4 + 3]) << 16);
          Pl[w][mi * 16 + l15][8 * ni + 2 * lhi + 0] = p01;
          Pl[w][mi * 16 + l15][8 * ni + 2 * lhi + 1] = p23;
        }
#pragma unroll
        for (int s = 8; s >= 1; s >>= 1)
#pragma unroll
          for (int k = 0; k < s; ++k) ps[k] += ps[k + s];
        float ls = ps[0];
        ls += __shfl_xor(ls, 16, 64);
        ls += __shfl_xor(ls, 32, 64);
        l_run[mi] = l_run[mi] * corr + ls;
#pragma unroll
        for (int nd = 0; nd < 4; ++nd)
#pragma unroll
          for (int r = 0; r < 4; ++r) acc_o[mi][nd][r] *= corr;
      }

      // PV swapped: acc_o[mi][nd] += mfma(A=V^T[d][key], B=P^T[q][key])
#pragma unroll
      for (int kc = 0; kc < 2; ++kc) {
        short8 pf[2];
#pragma unroll
        for (int mi = 0; mi < 2; ++mi)
          pf[mi] = *(const short8*)&Pl[w][mi * 16 + l15][kc * 16 + lhi * 4];
#pragma unroll
        for (int nd = 0; nd < 4; ++nd) {
          int row = nd * 16 + l15;
          short8 vf = *(const short8*)&Vt[cur][row][((kc * 4 + lhi) ^ (l15 & 7)) * 8];
#pragma unroll
          for (int mi = 0; mi < 2; ++mi)
            acc_o[mi][nd] = __builtin_amdgcn_mfma_f32_16x16x32_bf16(vf, pf[mi], acc_o[mi][nd], 0, 0, 0);
        }
      }
    }
    __syncthreads();  // cur reads done everywhere; nxt async writes landed
    cur = nxt;
  }

  // epilogue: O^T[d][q] -> head-major [16][4096][64], 8B packed stores
#pragma unroll
  for (int mi = 0; mi < 2; ++mi) {
    float inv = 1.f / l_run[mi];
    long s = (long)c * 512 + q0 + w * 32 + mi * 16 + l15;
#pragma unroll
    for (int nd = 0; nd < 4; ++nd) {
      us4 o;
#pragma unroll
      for (int r = 0; r < 4; ++r) o[r] = f2bf(acc_o[mi][nd][r] * inv);
      *(us4*)&outh[head_base + s * 64 + nd * 16 + lhi * 4] = o;
    }
  }
}

extern "C" void kernel_launch(void* const* d_in, const int* in_sizes, int n_in,
                              void* d_out, int out_size, void* d_ws, size_t ws_size,
                              hipStream_t stream) {
  const float* x = (const float*)d_in[0];      // [4096][1024]
  const float* w_qkv = (const float*)d_in[1];  // [1024][3072]
  const float* w_out = (const float*)d_in[2];  // [1024][1024]
  float* out = (float*)d_out;                  // [4096][1024]

  u16* xb = (u16*)d_ws;                        // 4M elems
  u16* wqkvT = xb + 4096 * 1024;               // 3M
  u16* woutT = wqkvT + 3072 * 1024;            // 1M
  u16* qh = woutT + 1024 * 1024;               // 4M  (later: attn out, head-major)
  u16* kh = qh + 16 * 4096 * 64;               // 4M
  u16* vh = kh + 16 * 4096 * 64;               // 4M
  u16* vt = xb;  // alias: x_bf16 dead after GEMM1   (total ws = 40 MB)

  cast_f32_to_bf16<<<2048, 256, 0, stream>>>(x, xb, 4096 * 1024 / 8);
  transpose_cast<<<dim3(96, 32), 256, 0, stream>>>(w_qkv, wqkvT, 1024, 3072);
  transpose_cast<<<dim3(32, 32), 256, 0, stream>>>(w_out, woutT, 1024, 1024);

  gemm_bf16<1, 128><<<dim3(24, 32), 256, 0, stream>>>(xb, wqkvT, nullptr, qh, kh, vh,
                                                      4096, 3072, 1024);
  transpose_v<<<dim3(128, 2, 16), 256, 0, stream>>>(vh, vt);
  attn_kernel<<<512, 256, 0, stream>>>(qh, kh, vt, qh);
  gemm_bf16<2, 64><<<dim3(16, 32), 256, 0, stream>>>(qh, woutT, out, nullptr, nullptr, nullptr,
                                                     4096, 1024, 1024);
}

// Round 9
// 175.085 us; speedup vs baseline: 1.3527x; 1.0423x over previous
//
#include <hip/hip_runtime.h>

// Problem constants: B=1, S=4096, D=1024, H=16, W=512, HD=64, C=8 chunks.
typedef __attribute__((ext_vector_type(8))) short short8;
typedef __attribute__((ext_vector_type(4))) float f32x4;
typedef __attribute__((ext_vector_type(4))) unsigned short us4;
typedef unsigned short u16;

__device__ __forceinline__ u16 f2bf(float f) {
  unsigned int u = __float_as_uint(f);
  u += 0x7fffu + ((u >> 16) & 1u);   // round-to-nearest-even
  return (u16)(u >> 16);
}

// async global->LDS, 16B per lane. LDS dest = wave-uniform base + lane*16.
__device__ __forceinline__ void gld16(const void* g, void* l) {
  __builtin_amdgcn_global_load_lds((const __attribute__((address_space(1))) void*)g,
                                   (__attribute__((address_space(3))) void*)l, 16, 0, 0);
}

// ---------------- cast f32 -> bf16 (8 elems/thread) ----------------
__global__ __launch_bounds__(256) void cast_f32_to_bf16(const float* __restrict__ in,
                                                        u16* __restrict__ out, int n8) {
  int i = blockIdx.x * 256 + threadIdx.x;
  if (i >= n8) return;
  const f32x4* p = (const f32x4*)in;
  f32x4 a = p[i * 2];
  f32x4 b = p[i * 2 + 1];
  short8 o;
#pragma unroll
  for (int j = 0; j < 4; ++j) o[j] = (short)f2bf(a[j]);
#pragma unroll
  for (int j = 0; j < 4; ++j) o[4 + j] = (short)f2bf(b[j]);
  ((short8*)out)[i] = o;
}

// ---------------- transpose [K][N] f32 -> [N][K] bf16 ----------------
__global__ __launch_bounds__(256) void transpose_cast(const float* __restrict__ w,
                                                      u16* __restrict__ wT, int K, int N) {
  __shared__ float tile[32][33];
  int n0 = blockIdx.x * 32, k0 = blockIdx.y * 32;
  int r = threadIdx.x >> 5;   // 0..7
  int c = threadIdx.x & 31;
#pragma unroll
  for (int i = 0; i < 4; ++i)
    tile[r + i * 8][c] = w[(size_t)(k0 + r + i * 8) * N + n0 + c];
  __syncthreads();
#pragma unroll
  for (int i = 0; i < 4; ++i)
    wT[(size_t)(n0 + r + i * 8) * K + k0 + c] = f2bf(tile[c][r + i * 8]);
}

// ---------------- per-head V transpose: [16][4096][64] -> [16][64][4096] ----------------
__global__ __launch_bounds__(256) void transpose_v(const u16* __restrict__ vh,
                                                   u16* __restrict__ vt) {
  __shared__ u16 tile[32][33];
  const int s0 = blockIdx.x * 32, d0 = blockIdx.y * 32, h = blockIdx.z;
  const long hb = (long)h * 4096 * 64;
  const long hb2 = (long)h * 64 * 4096;
  const int r = threadIdx.x >> 5, c = threadIdx.x & 31;
#pragma unroll
  for (int i = 0; i < 4; ++i)
    tile[r + i * 8][c] = vh[hb + (long)(s0 + r + i * 8) * 64 + d0 + c];
  __syncthreads();
#pragma unroll
  for (int i = 0; i < 4; ++i)
    vt[hb2 + (long)(d0 + r + i * 8) * 4096 + s0 + c] = tile[c][r + i * 8];
}

// ---------------- bf16 MFMA GEMM: C[M ties BM][N ties BN] = A * Bt^T ----------------
// m97 structure + XOR-swizzled LDS (pre-swizzled gld16 source, swizzled frag reads).
// MODE 0: A row-major [M][K], C f32.   MODE 1: A row-major, qkv split epilogue
// (q scaled by 0.125*log2e; q/k/v all [16][4096][64]).  MODE 2: A head-major
// [16][4096][64] (K=1024, BK=64 = one head per k-step), C f32.
template <int MODE, int BM, int BN>
__global__ __launch_bounds__(256) void gemm_bf16(
    const u16* __restrict__ A, const u16* __restrict__ Bt, float* __restrict__ C,
    u16* __restrict__ q_out, u16* __restrict__ k_out, u16* __restrict__ v_out,
    int M, int N, int K) {
  __shared__ __align__(16) u16 As[BM][64];
  __shared__ __align__(16) u16 Bs[BN][64];
  constexpr int MW = BM / 32;             // M-frags per wave
  constexpr int NW = BN / 32;             // N-frags per wave
  const int t = threadIdx.x;
  const int lane = t & 63;
  const int wid = t >> 6;
  const int wm = wid >> 1, wn = wid & 1;  // 2x2 waves
  const int l15 = lane & 15, lhi = lane >> 4;

  // XCD-chunked bijective swizzle (grid sizes are multiples of 8)
  const int nbx = gridDim.x;
  const int bid = blockIdx.y * nbx + blockIdx.x;
  const int cpx = (nbx * gridDim.y) >> 3;
  const int wg = (bid & 7) * cpx + (bid >> 3);
  const int m0 = (wg / nbx) * BM;
  const int n0 = (wg % nbx) * BN;

  const int srow = lane >> 3;                      // staging row within 8-row chunk
  const int scol = ((lane & 7) ^ (lane >> 3)) * 8; // pre-swizzled source unit

  f32x4 acc[MW][NW];
#pragma unroll
  for (int mi = 0; mi < MW; ++mi)
#pragma unroll
    for (int ni = 0; ni < NW; ++ni) acc[mi][ni] = (f32x4){0.f, 0.f, 0.f, 0.f};

  for (int k0 = 0; k0 < K; k0 += 64) {
    __syncthreads();  // readers done with LDS
#pragma unroll
    for (int i = 0; i < MW; ++i) {
      int cch = wid * MW + i;
      int row = cch * 8 + srow;
      const u16* src = (MODE == 2)
          ? &A[((size_t)(k0 >> 6) * 4096 + m0 + row) * 64 + scol]
          : &A[(size_t)(m0 + row) * K + k0 + scol];
      gld16(src, &As[cch * 8][0]);
    }
#pragma unroll
    for (int i = 0; i < NW; ++i) {
      int cch = wid * NW + i;
      int row = cch * 8 + srow;
      gld16(&Bt[(size_t)(n0 + row) * K + k0 + scol], &Bs[cch * 8][0]);
    }
    __syncthreads();
#pragma unroll
    for (int kc = 0; kc < 2; ++kc) {
      short8 af[MW], bf[NW];
#pragma unroll
      for (int mi = 0; mi < MW; ++mi) {
        int row = wm * (BM / 2) + mi * 16 + l15;
        af[mi] = *(const short8*)&As[row][((kc * 4 + lhi) ^ (l15 & 7)) * 8];
      }
#pragma unroll
      for (int ni = 0; ni < NW; ++ni) {
        int row = wn * (BN / 2) + ni * 16 + l15;
        bf[ni] = *(const short8*)&Bs[row][((kc * 4 + lhi) ^ (l15 & 7)) * 8];
      }
#pragma unroll
      for (int mi = 0; mi < MW; ++mi)
#pragma unroll
        for (int ni = 0; ni < NW; ++ni)
          acc[mi][ni] = __builtin_amdgcn_mfma_f32_16x16x32_bf16(af[mi], bf[ni], acc[mi][ni], 0, 0, 0);
    }
  }

  // epilogue; C/D layout: col = lane&15, row = (lane>>4)*4 + reg  [HW-verified]
  const float SCQ = 0.18033688011112042f;  // 0.125 * log2(e), folded into Q
#pragma unroll
  for (int mi = 0; mi < MW; ++mi)
#pragma unroll
    for (int ni = 0; ni < NW; ++ni)
#pragma unroll
      for (int r = 0; r < 4; ++r) {
        int row = m0 + wm * (BM / 2) + mi * 16 + lhi * 4 + r;
        int col = n0 + wn * (BN / 2) + ni * 16 + l15;
        float val = acc[mi][ni][r];
        if constexpr (MODE == 1) {
          int which = col >> 10;           // 0:q 1:k 2:v
          int d = col & 1023;
          int hh = d >> 6, hd = d & 63;
          if (which == 0)      q_out[((size_t)hh * 4096 + row) * 64 + hd] = f2bf(val * SCQ);
          else if (which == 1) k_out[((size_t)hh * 4096 + row) * 64 + hd] = f2bf(val);
          else                 v_out[((size_t)hh * 4096 + row) * 64 + hd] = f2bf(val);
        } else {
          C[(size_t)row * N + col] = val;
        }
      }
}

// ---------------- sliding-window flash attention (8-wave, swapped-QK^T) ----------------
// Grid: 512 blocks (XCD-chunked), 512 threads = 8 waves, 16 queries/wave.
// 16 waves/CU resident (vs 8 at 4-wave) — the latency-hiding lever.
// K and V^T double-buffered via global_load_lds (pre-swizzled source + swizzled
// reads); each wave stages one 8-row chunk of K and V per tile. Swapped QK^T:
// lane's column = ONE query -> lane-local softmax trees + 2 shfl_xor.
__global__ __launch_bounds__(512) void attn_kernel(
    const u16* __restrict__ qh,   // [16][4096][64] bf16 (pre-scaled)
    const u16* __restrict__ kh,   // [16][4096][64] bf16
    const u16* __restrict__ vt,   // [16][64][4096] bf16 (V^T per head)
    u16* __restrict__ outh) {     // [16][4096][64] bf16 (aliases qh)
  __shared__ __align__(16) u16 Ks[2][64][64];           // 16KB
  __shared__ __align__(16) u16 Vt[2][64][64];           // 16KB
  __shared__ __align__(16) unsigned int Pl[8][16][37];  // 18.5KB; [wave][q][key-pair]

  const int t = threadIdx.x;
  const int lane = t & 63;
  const int w = t >> 6;          // 0..7
  const int l15 = lane & 15;
  const int lhi = lane >> 4;

  // XCD-chunked swizzle: 2 heads per XCD -> K/V working set ~2MB < 4MB L2
  const int bid = blockIdx.x;
  const int wk = (bid & 7) * 64 + (bid >> 3);
  const int qt = wk & 3, c = (wk >> 2) & 7, h = wk >> 5;

  const long head_base = (long)h * 4096 * 64;
  const int q0 = qt * 128;  // query offset within chunk
  const long q_gbase = head_base + (long)(c * 512 + q0) * 64;

  // Q fragments (B-operand: row=l15=query, k=d); wave w owns queries q0+w*16..+15
  short8 qf[2];
#pragma unroll
  for (int kc = 0; kc < 2; ++kc)
    qf[kc] = *(const short8*)&qh[q_gbase + (long)(w * 16 + l15) * 64 + kc * 32 + lhi * 8];

  float m_run = -1e30f, l_run = 0.f;
  f32x4 acc_o[4];  // [nd]: D[d=nd*16+lhi*4+r][q=l15]
#pragma unroll
  for (int nd = 0; nd < 4; ++nd) acc_o[nd] = (f32x4){0.f, 0.f, 0.f, 0.f};

  const int kt_start = (c == 0) ? 8 : 0;     // chunk 0: no prev chunk
  const int kt_end = 2 * qt + 9;             // causal trim
  const long kv_base = head_base + ((long)c - 1) * 512 * 64;       // K rows
  const long vt_hb = (long)h * 64 * 4096 + ((long)c - 1) * 512;    // V^T cols

  const int srow = lane >> 3;                           // 0..7 within chunk
  const int sunit8 = ((lane & 7) ^ (lane >> 3)) * 8;    // pre-swizzled source unit

  // prologue: wave w stages K chunk w (8 rows) + V^T chunk w into buffer 0
  {
    const int j0 = kt_start * 64;
    gld16(&kh[kv_base + (long)(j0 + w * 8 + srow) * 64 + sunit8], &Ks[0][w * 8][0]);
    gld16(&vt[vt_hb + (long)(w * 8 + srow) * 4096 + j0 + sunit8], &Vt[0][w * 8][0]);
  }
  __syncthreads();

  int cur = 0;
  for (int kt = kt_start; kt <= kt_end; ++kt) {
    const int j0 = kt * 64;
    const int nxt = cur ^ 1;

    // issue next tile's async loads early; latency hides under this tile's compute
    if (kt < kt_end) {
      const int j0n = j0 + 64;
      gld16(&kh[kv_base + (long)(j0n + w * 8 + srow) * 64 + sunit8], &Ks[nxt][w * 8][0]);
      gld16(&vt[vt_hb + (long)(w * 8 + srow) * 4096 + j0n + sunit8], &Vt[nxt][w * 8][0]);
    }

    const bool active = (j0 <= q0 + w * 16 + 15 + 512);  // wave-level causal skip
    if (active) {
      // QK^T swapped: sa[ni] = D[key=j0+16ni+4lhi+r][query=w*16+l15]
      f32x4 sa[4];
#pragma unroll
      for (int ni = 0; ni < 4; ++ni) sa[ni] = (f32x4){0.f, 0.f, 0.f, 0.f};
#pragma unroll
      for (int kc = 0; kc < 2; ++kc) {
        short8 kf[4];
#pragma unroll
        for (int ni = 0; ni < 4; ++ni) {
          int row = ni * 16 + l15;
          kf[ni] = *(const short8*)&Ks[cur][row][((kc * 4 + lhi) ^ (l15 & 7)) * 8];
        }
#pragma unroll
        for (int ni = 0; ni < 4; ++ni)
          sa[ni] = __builtin_amdgcn_mfma_f32_16x16x32_bf16(kf[ni], qf[kc], sa[ni], 0, 0, 0);
      }

      const int qloc = q0 + w * 16 + l15;  // this lane's query
      if (j0 + 63 > q0 + w * 16 + 512) {   // boundary tile: causal mask
        const int lim = qloc + 512 - j0 - 4 * lhi;   // key-off (16ni+r) <= lim
#pragma unroll
        for (int ni = 0; ni < 4; ++ni)
#pragma unroll
          for (int r = 0; r < 4; ++r)
            if (16 * ni + r > lim) sa[ni][r] = -1e30f;
      }
      // lane-local max tree over 16 values, then 2-round shfl across lhi group
      float v[16];
#pragma unroll
      for (int ni = 0; ni < 4; ++ni)
#pragma unroll
        for (int r = 0; r < 4; ++r) v[ni * 4 + r] = sa[ni][r];
#pragma unroll
      for (int s = 8; s >= 1; s >>= 1)
#pragma unroll
        for (int k = 0; k < s; ++k) v[k] = fmaxf(v[k], v[k + s]);
      float tm = v[0];
      tm = fmaxf(tm, __shfl_xor(tm, 16, 64));
      tm = fmaxf(tm, __shfl_xor(tm, 32, 64));

      float mn = fmaxf(m_run, tm);
      float corr = __builtin_amdgcn_exp2f(m_run - mn);
      m_run = mn;

      // P = exp2(S - m), pack pairs -> u32, lane-local sum tree
      float ps[16];
#pragma unroll
      for (int ni = 0; ni < 4; ++ni) {
#pragma unroll
        for (int r = 0; r < 4; ++r) ps[ni * 4 + r] = __builtin_amdgcn_exp2f(sa[ni][r] - mn);
        unsigned int p01 = (unsigned int)f2bf(ps[ni * 4 + 0]) | ((unsigned int)f2bf(ps[ni * 4 + 1]) << 16);
        unsigned int p23 = (unsigned int)f2bf(ps[ni * 4 + 2]) | ((unsigned int)f2bf(ps[ni * 4 + 3]) << 16);
        Pl[w][l15][8 * ni + 2 * lhi + 0] = p01;
        Pl[w][l15][8 * ni + 2 * lhi + 1] = p23;
      }
#pragma unroll
      for (int s = 8; s >= 1; s >>= 1)
#pragma unroll
        for (int k = 0; k < s; ++k) ps[k] += ps[k + s];
      float ls = ps[0];
      ls += __shfl_xor(ls, 16, 64);
      ls += __shfl_xor(ls, 32, 64);
      l_run = l_run * corr + ls;
#pragma unroll
      for (int nd = 0; nd < 4; ++nd)
#pragma unroll
        for (int r = 0; r < 4; ++r) acc_o[nd][r] *= corr;

      // PV swapped: acc_o[nd] += mfma(A=V^T[d][key], B=P^T[q][key])
#pragma unroll
      for (int kc = 0; kc < 2; ++kc) {
        short8 pf = *(const short8*)&Pl[w][l15][kc * 16 + lhi * 4];
#pragma unroll
        for (int nd = 0; nd < 4; ++nd) {
          int row = nd * 16 + l15;
          short8 vf = *(const short8*)&Vt[cur][row][((kc * 4 + lhi) ^ (l15 & 7)) * 8];
          acc_o[nd] = __builtin_amdgcn_mfma_f32_16x16x32_bf16(vf, pf, acc_o[nd], 0, 0, 0);
        }
      }
    }
    __syncthreads();  // cur reads done everywhere; nxt async writes landed
    cur = nxt;
  }

  // epilogue: O^T[d][q] -> head-major [16][4096][64], 8B packed stores
  {
    float inv = 1.f / l_run;
    long s = (long)c * 512 + q0 + w * 16 + l15;
#pragma unroll
    for (int nd = 0; nd < 4; ++nd) {
      us4 o;
#pragma unroll
      for (int r = 0; r < 4; ++r) o[r] = f2bf(acc_o[nd][r] * inv);
      *(us4*)&outh[head_base + s * 64 + nd * 16 + lhi * 4] = o;
    }
  }
}

extern "C" void kernel_launch(void* const* d_in, const int* in_sizes, int n_in,
                              void* d_out, int out_size, void* d_ws, size_t ws_size,
                              hipStream_t stream) {
  const float* x = (const float*)d_in[0];      // [4096][1024]
  const float* w_qkv = (const float*)d_in[1];  // [1024][3072]
  const float* w_out = (const float*)d_in[2];  // [1024][1024]
  float* out = (float*)d_out;                  // [4096][1024]

  u16* xb = (u16*)d_ws;                        // 4M elems
  u16* wqkvT = xb + 4096 * 1024;               // 3M
  u16* woutT = wqkvT + 3072 * 1024;            // 1M
  u16* qh = woutT + 1024 * 1024;               // 4M  (later: attn out, head-major)
  u16* kh = qh + 16 * 4096 * 64;               // 4M
  u16* vh = kh + 16 * 4096 * 64;               // 4M
  u16* vt = xb;  // alias: x_bf16 dead after GEMM1   (total ws = 40 MB)

  cast_f32_to_bf16<<<2048, 256, 0, stream>>>(x, xb, 4096 * 1024 / 8);
  transpose_cast<<<dim3(96, 32), 256, 0, stream>>>(w_qkv, wqkvT, 1024, 3072);
  transpose_cast<<<dim3(32, 32), 256, 0, stream>>>(w_out, woutT, 1024, 1024);

  gemm_bf16<1, 128, 128><<<dim3(24, 32), 256, 0, stream>>>(xb, wqkvT, nullptr, qh, kh, vh,
                                                           4096, 3072, 1024);
  transpose_v<<<dim3(128, 2, 16), 256, 0, stream>>>(vh, vt);
  attn_kernel<<<512, 512, 0, stream>>>(qh, kh, vt, qh);
  gemm_bf16<2, 64, 64><<<dim3(16, 64), 256, 0, stream>>>(qh, woutT, out, nullptr, nullptr, nullptr,
                                                         4096, 1024, 1024);
}